// Round 8
// baseline (467.151 us; speedup 1.0000x reference)
//
#include <hip/hip_runtime.h>

#define FEAT 128

typedef __attribute__((ext_vector_type(8))) short short8;   // 8 bf16 = 4 VGPRs
typedef __attribute__((ext_vector_type(4))) float f32x4;

__device__ __forceinline__ unsigned int bf16rtn(float f) {
    unsigned int u = __float_as_uint(f);
    return (u + 0x7fffu + ((u >> 16) & 1u)) >> 16;   // round-to-nearest-even
}
__device__ __forceinline__ float bf16tof(unsigned int h) { return __uint_as_float(h << 16); }
__device__ __forceinline__ float bf16lo(unsigned int v) { return __uint_as_float(v << 16); }
__device__ __forceinline__ float bf16hi(unsigned int v) { return __uint_as_float(v & 0xffff0000u); }

// ---------------------------------------------------------------- utilities
__global__ void zero_kernel(float* __restrict__ p, int n) {
    int i = blockIdx.x * blockDim.x + threadIdx.x;
    if (i < n) p[i] = 0.0f;
}

// ---------------------------------------------------------------- bucket sort (no global atomics)
// K1: per-block LDS histogram over col>>8 (nbuck buckets), 4096 edges/block.
__global__ __launch_bounds__(256) void hist_kernel(const int* __restrict__ col,
                                                   int* __restrict__ ghist,
                                                   int E, int nblk, int nbuck) {
    __shared__ int h[256];
    const int t = threadIdx.x, b = blockIdx.x;
    h[t] = 0;
    __syncthreads();
    const int base = b * 4096;
#pragma unroll
    for (int i = 0; i < 16; ++i) {
        int e = base + i * 256 + t;
        if (e < E) atomicAdd(&h[col[e] >> 8], 1);
    }
    __syncthreads();
    if (t < nbuck) ghist[t * nblk + b] = h[t];   // digit-major for the scan
}

// ---------------------------------------------------------------- scan (exclusive, 3-phase)
__global__ __launch_bounds__(256) void scan_block_kernel(const int* __restrict__ cnt,
                                                         int* __restrict__ out,
                                                         int* __restrict__ bsum, int M) {
    __shared__ int s[256];
    int t = threadIdx.x;
    int i = blockIdx.x * 256 + t;
    int own = (i < M) ? cnt[i] : 0;
    s[t] = own;
    for (int off = 1; off < 256; off <<= 1) {
        __syncthreads();
        int v = (t >= off) ? s[t - off] : 0;
        __syncthreads();
        s[t] += v;
    }
    __syncthreads();
    if (i < M) out[i] = s[t] - own;
    if (t == 255) bsum[blockIdx.x] = s[255];
}

__global__ __launch_bounds__(256) void scan_bsum_kernel(int* __restrict__ bsum, int nb) {
    __shared__ int s[256];
    int t = threadIdx.x;
    int own = (t < nb) ? bsum[t] : 0;
    s[t] = own;
    for (int off = 1; off < 256; off <<= 1) {
        __syncthreads();
        int v = (t >= off) ? s[t - off] : 0;
        __syncthreads();
        s[t] += v;
    }
    __syncthreads();
    if (t < nb) bsum[t] = s[t] - own;
}

__global__ __launch_bounds__(256) void scan_add_kernel(int* __restrict__ out,
                                                       const int* __restrict__ bsum,
                                                       int M, int total) {
    int i = blockIdx.x * 256 + threadIdx.x;
    if (i < M) out[i] += bsum[blockIdx.x];
    if (i == M) out[M] = total;
}

// K3: scatter into bucket-grouped order. LDS cursors seeded from gbase.
// payload: x = (col<<16) | row  (both < 65536), y = ew bits.
__global__ __launch_bounds__(256) void scatter1_kernel(const int* __restrict__ row,
                                                       const int* __restrict__ col,
                                                       const float* __restrict__ ew,
                                                       const int* __restrict__ gbase,
                                                       uint2* __restrict__ bedge,
                                                       int E, int nblk, int nbuck) {
    __shared__ int cur[256];
    const int t = threadIdx.x, b = blockIdx.x;
    if (t < nbuck) cur[t] = gbase[t * nblk + b];
    __syncthreads();
    const int base = b * 4096;
#pragma unroll
    for (int i = 0; i < 16; ++i) {
        int e = base + i * 256 + t;
        if (e < E) {
            int c = col[e];
            int slot = atomicAdd(&cur[c >> 8], 1);
            bedge[slot] = make_uint2(((unsigned)c << 16) | (unsigned)row[e],
                                     __float_as_uint(ew[e]));
        }
    }
}

// K4: one block per bucket (256 nodes). LDS count + weighted-degree sum per
// node -> rowptr + dinv; then LDS-cursor scatter to final per-node order with
// w*dinv[col] folded in.
__global__ __launch_bounds__(256) void bucket_kernel(const uint2* __restrict__ bedge,
                                                     const int* __restrict__ gbase,
                                                     int* __restrict__ rowptr,
                                                     float* __restrict__ dinv,
                                                     uint2* __restrict__ sedge,
                                                     int N, int E, int nblk, int nbuck) {
    __shared__ int lcnt[256];
    __shared__ float lw[256];
    __shared__ int lscan[256];
    __shared__ int lcur[256];
    __shared__ float ldv[256];

    const int d = blockIdx.x, t = threadIdx.x;
    const int base = gbase[d * nblk];
    const int end  = (d == nbuck - 1) ? E : gbase[(d + 1) * nblk];

    lcnt[t] = 0;
    lw[t] = 0.f;
    __syncthreads();
    for (int i = base + t; i < end; i += 256) {
        uint2 p = bedge[i];
        int c = (p.x >> 16) & 255;
        atomicAdd(&lcnt[c], 1);
        atomicAdd(&lw[c], __uint_as_float(p.y));
    }
    __syncthreads();
    int own = lcnt[t];
    lscan[t] = own;
    for (int off = 1; off < 256; off <<= 1) {
        __syncthreads();
        int v = (t >= off) ? lscan[t - off] : 0;
        __syncthreads();
        lscan[t] += v;
    }
    __syncthreads();
    int excl = lscan[t] - own;
    lcur[t] = base + excl;
    float wsum = lw[t];
    float dv = (wsum > 0.f) ? rsqrtf(wsum) : 0.f;
    ldv[t] = dv;
    int node = d * 256 + t;
    if (node < N) {
        rowptr[node] = base + excl;
        dinv[node] = dv;
    }
    if (d == nbuck - 1 && t == 0) rowptr[N] = E;
    __syncthreads();
    for (int i = base + t; i < end; i += 256) {
        uint2 p = bedge[i];
        int c = (p.x >> 16) & 255;
        int slot = atomicAdd(&lcur[c], 1);
        sedge[slot] = make_uint2(p.x & 0xFFFFu,
                                 __float_as_uint(__uint_as_float(p.y) * ldv[c]));
    }
}

// K5: finish norm: w *= dinv[row]  (dinv is 200KB, L2-resident)
__global__ void norm_kernel(uint2* __restrict__ sedge, const float* __restrict__ dinv, int E) {
    int i = blockIdx.x * blockDim.x + threadIdx.x;
    if (i < E) {
        uint2 p = sedge[i];
        p.y = __float_as_uint(__uint_as_float(p.y) * dinv[p.x]);
        sedge[i] = p;
    }
}

// all 3 weights -> transposed split planes Wt[c][k] bf16 hi/lo, one launch
__global__ void convw_kernel(const float* __restrict__ W0, const float* __restrict__ W1,
                             const float* __restrict__ W2,
                             unsigned short* __restrict__ Whi, unsigned short* __restrict__ Wlo) {
    int i = blockIdx.x * blockDim.x + threadIdx.x;  // 16384 per weight
    int which = blockIdx.y;
    const float* W = (which == 0) ? W0 : (which == 1) ? W1 : W2;
    int c = i >> 7, k = i & 127;
    float w = W[(size_t)k * FEAT + c];
    unsigned int h = bf16rtn(w);
    size_t off = (size_t)which * 16384 + (size_t)c * FEAT + k;
    Whi[off] = (unsigned short)h;
    Wlo[off] = (unsigned short)bf16rtn(w - bf16tof(h));
}

// ---------------------------------------------------------------- MFMA GEMM
// Same as R4 except the epilogue writes PLANE-MAJOR hb4: plane p holds
// features [32p, 32p+32) as 64B/node rows -> each plane is 3.2 MB and fits a
// 4-MB per-XCD L2 during the agg phase that gathers it.
__global__ __launch_bounds__(256) void gemm_mfma_kernel(
    const float* __restrict__ X,
    const unsigned short* __restrict__ Wthi, const unsigned short* __restrict__ Wtlo,
    unsigned int* __restrict__ hb4,   // 4 planes x N x 16 uints (packed bf16)
    int N)
{
    __shared__ unsigned short xh[64 * 128];
    __shared__ unsigned short xl[64 * 128];
    __shared__ unsigned short wh[64 * 128];
    __shared__ unsigned short wl[64 * 128];

    const int tid = threadIdx.x;
    const int r0 = blockIdx.x * 64;
    const int cb = blockIdx.y;       // col half: 0 or 1

#pragma unroll
    for (int it = 0; it < 4; ++it) {
        int idx = it * 256 + tid;
        int c = idx >> 4;
        int k8 = (idx & 15) * 8;
        int sw = k8 ^ ((c & 7) << 3);
        size_t src = (size_t)(cb * 64 + c) * FEAT + k8;
        *(short8*)&wh[c * 128 + sw] = *(const short8*)(Wthi + src);
        *(short8*)&wl[c * 128 + sw] = *(const short8*)(Wtlo + src);
    }
#pragma unroll
    for (int it = 0; it < 8; ++it) {
        int idx = it * 256 + tid;
        int r = idx >> 5;
        int kc = (idx & 31) * 4;
        int gr = r0 + r;
        float4 v = make_float4(0.f, 0.f, 0.f, 0.f);
        if (gr < N) v = *(const float4*)(X + (size_t)gr * FEAT + kc);
        unsigned int h0 = bf16rtn(v.x), h1 = bf16rtn(v.y);
        unsigned int h2 = bf16rtn(v.z), h3 = bf16rtn(v.w);
        ushort4 hv = make_ushort4((unsigned short)h0, (unsigned short)h1,
                                  (unsigned short)h2, (unsigned short)h3);
        ushort4 lv = make_ushort4((unsigned short)bf16rtn(v.x - bf16tof(h0)),
                                  (unsigned short)bf16rtn(v.y - bf16tof(h1)),
                                  (unsigned short)bf16rtn(v.z - bf16tof(h2)),
                                  (unsigned short)bf16rtn(v.w - bf16tof(h3)));
        int sw = kc ^ ((r & 7) << 3);
        *(ushort4*)&xh[r * 128 + sw] = hv;
        *(ushort4*)&xl[r * 128 + sw] = lv;
    }
    __syncthreads();

    const int lane = tid & 63;
    const int wv = tid >> 6;
    const int m = lane & 15;
    const int quad = lane >> 4;
    const int arow = wv * 16 + m;

    f32x4 acc[4];
#pragma unroll
    for (int ct = 0; ct < 4; ++ct) acc[ct] = (f32x4){0.f, 0.f, 0.f, 0.f};

#pragma unroll
    for (int kt = 0; kt < 4; ++kt) {
        const int k0 = kt * 32 + quad * 8;
        const int aw = k0 ^ ((arow & 7) << 3);
        short8 ah = *(const short8*)&xh[arow * 128 + aw];
        short8 al = *(const short8*)&xl[arow * 128 + aw];
#pragma unroll
        for (int ct = 0; ct < 4; ++ct) {
            int bc = ct * 16 + m;
            int bw = k0 ^ ((bc & 7) << 3);
            short8 bh = *(const short8*)&wh[bc * 128 + bw];
            short8 bl = *(const short8*)&wl[bc * 128 + bw];
            acc[ct] = __builtin_amdgcn_mfma_f32_16x16x32_bf16(ah, bh, acc[ct], 0, 0, 0);
            acc[ct] = __builtin_amdgcn_mfma_f32_16x16x32_bf16(ah, bl, acc[ct], 0, 0, 0);
            acc[ct] = __builtin_amdgcn_mfma_f32_16x16x32_bf16(al, bh, acc[ct], 0, 0, 0);
        }
    }

    __syncthreads();
    unsigned short* cl = xh;
#pragma unroll
    for (int ct = 0; ct < 4; ++ct)
#pragma unroll
        for (int reg = 0; reg < 4; ++reg) {
            int rrow = wv * 16 + quad * 4 + reg;
            cl[rrow * 72 + ct * 16 + m] = (unsigned short)bf16rtn(acc[ct][reg]);
        }
    __syncthreads();
#pragma unroll
    for (int it = 0; it < 2; ++it) {
        int idx = it * 256 + tid;
        int r = idx >> 3;
        int c4 = (idx & 7) * 4;      // uint offset within 32-uint half-row
        int gr = r0 + r;
        if (gr < N) {
            uint4 pv = *(const uint4*)&cl[r * 72 + c4 * 2];
            int u = cb * 32 + c4;    // global uint index 0..60
            int p = u >> 4;          // plane 0..3
            int jj = u & 15;         // 0,4,8,12 (16B-aligned)
            *(uint4*)(hb4 + (((size_t)p * N + gr) << 4) + jj) = pv;
        }
    }
}

// ---------------------------------------------------------------- agg v5: phased plane gather
// grid (ceil(N/4), 4): blockIdx.y = feature plane p (3.2MB, L2-resident per
// XCD during its phase). One wave per node per plane. Quarter q handles edge
// slot q of each 4-edge group; lane j in [0,16) reads uint j of the 64B slice
// -> one load instruction gathers 4 edges. 16 edges (4 gathers) in flight.
// Cross-quarter shfl_xor reduce; lanes 0-15 add bias (+relu) and store float2.
template <int RELU>
__global__ __launch_bounds__(256) void agg_kernel(
    const int* __restrict__ rowptr, const uint2* __restrict__ sedge,
    const unsigned int* __restrict__ hb4, const float* __restrict__ bias,
    float* __restrict__ outX, int N)
{
    const int node = blockIdx.x * 4 + (threadIdx.x >> 6);
    if (node >= N) return;
    const int p = blockIdx.y;
    const int lane = threadIdx.x & 63;
    const int q = lane >> 4;
    const int j = lane & 15;
    const int s = rowptr[node];
    const int e = rowptr[node + 1];
    const unsigned int* plane = hb4 + ((size_t)p * N << 4);

    float a0 = 0.f, a1 = 0.f;
    for (int gb = s; gb < e; gb += 16) {
        int i0 = gb + q, i1 = gb + 4 + q, i2 = gb + 8 + q, i3 = gb + 12 + q;
        uint2 c0 = (i0 < e) ? sedge[i0] : make_uint2(0u, 0u);
        uint2 c1 = (i1 < e) ? sedge[i1] : make_uint2(0u, 0u);
        uint2 c2 = (i2 < e) ? sedge[i2] : make_uint2(0u, 0u);
        uint2 c3 = (i3 < e) ? sedge[i3] : make_uint2(0u, 0u);
        unsigned v0 = plane[((size_t)c0.x << 4) + j];
        unsigned v1 = plane[((size_t)c1.x << 4) + j];
        unsigned v2 = plane[((size_t)c2.x << 4) + j];
        unsigned v3 = plane[((size_t)c3.x << 4) + j];
        float w0 = __uint_as_float(c0.y), w1 = __uint_as_float(c1.y);
        float w2 = __uint_as_float(c2.y), w3 = __uint_as_float(c3.y);
        a0 = fmaf(w0, bf16lo(v0), a0);  a1 = fmaf(w0, bf16hi(v0), a1);
        a0 = fmaf(w1, bf16lo(v1), a0);  a1 = fmaf(w1, bf16hi(v1), a1);
        a0 = fmaf(w2, bf16lo(v2), a0);  a1 = fmaf(w2, bf16hi(v2), a1);
        a0 = fmaf(w3, bf16lo(v3), a0);  a1 = fmaf(w3, bf16hi(v3), a1);
    }

    // sum the 4 quarters (same feature pair j across q)
    a0 += __shfl_xor(a0, 16);  a0 += __shfl_xor(a0, 32);
    a1 += __shfl_xor(a1, 16);  a1 += __shfl_xor(a1, 32);

    if (q == 0) {
        float2 bv = *(const float2*)(bias + p * 32 + j * 2);
        a0 += bv.x;  a1 += bv.y;
        if (RELU) { a0 = fmaxf(a0, 0.f); a1 = fmaxf(a1, 0.f); }
        *(float2*)(outX + (size_t)node * FEAT + p * 32 + j * 2) = make_float2(a0, a1);
    }
}

// ---------------------------------------------------------------- readout v2
// grid (G, 8): 8 chunks per graph, 4-deep ILP, one atomicAdd per thread.
__global__ __launch_bounds__(128) void readout_kernel(const float* __restrict__ h,
                                                      const int* __restrict__ batch,
                                                      float* __restrict__ ro, int N) {
    const int g = blockIdx.x;
    const int chunk = blockIdx.y;
    const int j = threadIdx.x;
    int lo = 0, hi = N;
    while (lo < hi) { int mid = (lo + hi) >> 1; if (batch[mid] < g) lo = mid + 1; else hi = mid; }
    int lo2 = lo, hi2 = N;
    while (lo2 < hi2) { int mid = (lo2 + hi2) >> 1; if (batch[mid] < g + 1) lo2 = mid + 1; else hi2 = mid; }
    const int len = lo2 - lo;
    const int per = (len + 7) >> 3;
    const int cs = lo + chunk * per;
    const int ce = min(lo2, cs + per);

    float s0 = 0.f, s1 = 0.f, s2 = 0.f, s3 = 0.f;
    int n = cs;
    for (; n + 4 <= ce; n += 4) {
        s0 += h[(size_t)n * FEAT + j];
        s1 += h[(size_t)(n + 1) * FEAT + j];
        s2 += h[(size_t)(n + 2) * FEAT + j];
        s3 += h[(size_t)(n + 3) * FEAT + j];
    }
    for (; n < ce; ++n) s0 += h[(size_t)n * FEAT + j];
    float acc = (s0 + s1) + (s2 + s3);
    if (cs < ce) atomicAdd(&ro[(size_t)g * FEAT + j], acc);
}

// ---------------------------------------------------------------- launch
static inline size_t align256(size_t x) { return (x + 255) & ~(size_t)255; }

extern "C" void kernel_launch(void* const* d_in, const int* in_sizes, int n_in,
                              void* d_out, int out_size, void* d_ws, size_t ws_size,
                              hipStream_t stream) {
    const float* gx    = (const float*)d_in[0];
    const int*   ei    = (const int*)d_in[1];
    const int*   batch = (const int*)d_in[2];
    const float* ew    = (const float*)d_in[3];
    const float* W1 = (const float*)d_in[4];
    const float* b1 = (const float*)d_in[5];
    const float* W2 = (const float*)d_in[6];
    const float* b2 = (const float*)d_in[7];
    const float* W3 = (const float*)d_in[8];
    const float* b3 = (const float*)d_in[9];

    const int N = in_sizes[0] / FEAT;            // 50000
    const int E = in_sizes[3];                   // 800000
    const int G = (out_size - N * FEAT) / FEAT;  // 256

    const int* row = ei;
    const int* col = ei + E;

    const int nbuck = (N + 255) >> 8;            // 196
    const int nblk  = (E + 4095) >> 12;          // 196
    const int M     = nbuck * nblk;              // 38416

    // ---- workspace layout
    char* ws = (char*)d_ws;
    int*   rowptr = (int*)ws;         ws += align256((size_t)(N + 1) * 4);
    float* dinv   = (float*)ws;       ws += align256((size_t)N * 4);
    int*   ghist  = (int*)ws;         ws += align256((size_t)M * 4);
    int*   gbase  = (int*)ws;         ws += align256((size_t)(M + 1) * 4);
    int*   bsum   = (int*)ws;         ws += align256(256 * 4);
    uint2* bedge  = (uint2*)ws;       ws += align256((size_t)E * 8);
    uint2* sedge  = (uint2*)ws;       ws += align256((size_t)E * 8);
    unsigned int* hb4 = (unsigned int*)ws;  ws += align256((size_t)N * 64 * 4);
    float* bufX   = (float*)ws;       ws += align256((size_t)N * FEAT * 4);
    unsigned short* Wh = (unsigned short*)ws; ws += align256((size_t)3 * 16384 * 2);
    unsigned short* Wl = (unsigned short*)ws; ws += align256((size_t)3 * 16384 * 2);

    float* h_out = (float*)d_out;
    float* ro    = h_out + (size_t)N * FEAT;

    // ---- bucket-sorted CSR build (no global atomics)
    hist_kernel<<<nblk, 256, 0, stream>>>(col, ghist, E, nblk, nbuck);
    const int snb = (M + 255) / 256;
    scan_block_kernel<<<snb, 256, 0, stream>>>(ghist, gbase, bsum, M);
    scan_bsum_kernel<<<1, 256, 0, stream>>>(bsum, snb);
    scan_add_kernel<<<snb + 1, 256, 0, stream>>>(gbase, bsum, M, E);
    scatter1_kernel<<<nblk, 256, 0, stream>>>(row, col, ew, gbase, bedge, E, nblk, nbuck);
    bucket_kernel<<<nbuck, 256, 0, stream>>>(bedge, gbase, rowptr, dinv, sedge, N, E, nblk, nbuck);
    norm_kernel<<<(E + 255) / 256, 256, 0, stream>>>(sedge, dinv, E);

    // ---- weight conversion (one launch, 3 weights)
    convw_kernel<<<dim3(64, 3), 256, 0, stream>>>(W1, W2, W3, Wh, Wl);

    dim3 ggrid((N + 63) / 64, 2);
    dim3 agrid((N + 3) / 4, 4);

    // ---- layer 1 (GEMM reads gx fp32 directly)
    gemm_mfma_kernel<<<ggrid, 256, 0, stream>>>(gx, Wh, Wl, hb4, N);
    agg_kernel<1><<<agrid, 256, 0, stream>>>(rowptr, sedge, hb4, b1, bufX, N);
    // ---- layer 2
    gemm_mfma_kernel<<<ggrid, 256, 0, stream>>>(bufX, Wh + 16384, Wl + 16384, hb4, N);
    agg_kernel<1><<<agrid, 256, 0, stream>>>(rowptr, sedge, hb4, b2, bufX, N);
    // ---- layer 3
    gemm_mfma_kernel<<<ggrid, 256, 0, stream>>>(bufX, Wh + 32768, Wl + 32768, hb4, N);
    agg_kernel<0><<<agrid, 256, 0, stream>>>(rowptr, sedge, hb4, b3, h_out, N);
    // ---- readout: parallel chunked segment-sum (sorted batch)
    zero_kernel<<<(G * FEAT + 255) / 256, 256, 0, stream>>>(ro, G * FEAT);
    readout_kernel<<<dim3(G, 8), 128, 0, stream>>>(h_out, batch, ro, N);
}

// Round 9
// 331.801 us; speedup vs baseline: 1.4079x; 1.4079x over previous
//
#include <hip/hip_runtime.h>

#define FEAT 128

typedef __attribute__((ext_vector_type(8))) short short8;   // 8 bf16 = 4 VGPRs
typedef __attribute__((ext_vector_type(4))) float f32x4;

__device__ __forceinline__ unsigned int bf16rtn(float f) {
    unsigned int u = __float_as_uint(f);
    return (u + 0x7fffu + ((u >> 16) & 1u)) >> 16;   // round-to-nearest-even
}
__device__ __forceinline__ float bf16tof(unsigned int h) { return __uint_as_float(h << 16); }
__device__ __forceinline__ float bf16lo(unsigned int v) { return __uint_as_float(v << 16); }
__device__ __forceinline__ float bf16hi(unsigned int v) { return __uint_as_float(v & 0xffff0000u); }

// ---------------------------------------------------------------- utilities
__global__ void zero_kernel(float* __restrict__ p, int n) {
    int i = blockIdx.x * blockDim.x + threadIdx.x;
    if (i < n) p[i] = 0.0f;
}

// ---------------------------------------------------------------- bucket sort (no global atomics)
// K1: per-block LDS histogram over col>>8 (nbuck buckets), 4096 edges/block.
__global__ __launch_bounds__(256) void hist_kernel(const int* __restrict__ col,
                                                   int* __restrict__ ghist,
                                                   int E, int nblk, int nbuck) {
    __shared__ int h[256];
    const int t = threadIdx.x, b = blockIdx.x;
    h[t] = 0;
    __syncthreads();
    const int base = b * 4096;
#pragma unroll
    for (int i = 0; i < 16; ++i) {
        int e = base + i * 256 + t;
        if (e < E) atomicAdd(&h[col[e] >> 8], 1);
    }
    __syncthreads();
    if (t < nbuck) ghist[t * nblk + b] = h[t];   // digit-major for the scan
}

// ---------------------------------------------------------------- scan (exclusive, 3-phase)
__global__ __launch_bounds__(256) void scan_block_kernel(const int* __restrict__ cnt,
                                                         int* __restrict__ out,
                                                         int* __restrict__ bsum, int M) {
    __shared__ int s[256];
    int t = threadIdx.x;
    int i = blockIdx.x * 256 + t;
    int own = (i < M) ? cnt[i] : 0;
    s[t] = own;
    for (int off = 1; off < 256; off <<= 1) {
        __syncthreads();
        int v = (t >= off) ? s[t - off] : 0;
        __syncthreads();
        s[t] += v;
    }
    __syncthreads();
    if (i < M) out[i] = s[t] - own;
    if (t == 255) bsum[blockIdx.x] = s[255];
}

__global__ __launch_bounds__(256) void scan_bsum_kernel(int* __restrict__ bsum, int nb) {
    __shared__ int s[256];
    int t = threadIdx.x;
    int own = (t < nb) ? bsum[t] : 0;
    s[t] = own;
    for (int off = 1; off < 256; off <<= 1) {
        __syncthreads();
        int v = (t >= off) ? s[t - off] : 0;
        __syncthreads();
        s[t] += v;
    }
    __syncthreads();
    if (t < nb) bsum[t] = s[t] - own;
}

__global__ __launch_bounds__(256) void scan_add_kernel(int* __restrict__ out,
                                                       const int* __restrict__ bsum,
                                                       int M, int total) {
    int i = blockIdx.x * 256 + threadIdx.x;
    if (i < M) out[i] += bsum[blockIdx.x];
    if (i == M) out[M] = total;
}

// K3: scatter into bucket-grouped order. LDS cursors seeded from gbase.
// payload: x = (col<<16) | row  (both < 65536), y = ew bits.
__global__ __launch_bounds__(256) void scatter1_kernel(const int* __restrict__ row,
                                                       const int* __restrict__ col,
                                                       const float* __restrict__ ew,
                                                       const int* __restrict__ gbase,
                                                       uint2* __restrict__ bedge,
                                                       int E, int nblk, int nbuck) {
    __shared__ int cur[256];
    const int t = threadIdx.x, b = blockIdx.x;
    if (t < nbuck) cur[t] = gbase[t * nblk + b];
    __syncthreads();
    const int base = b * 4096;
#pragma unroll
    for (int i = 0; i < 16; ++i) {
        int e = base + i * 256 + t;
        if (e < E) {
            int c = col[e];
            int slot = atomicAdd(&cur[c >> 8], 1);
            bedge[slot] = make_uint2(((unsigned)c << 16) | (unsigned)row[e],
                                     __float_as_uint(ew[e]));
        }
    }
}

// K4: one block per bucket (256 nodes). LDS count + weighted-degree sum per
// node -> rowptr + dinv; then LDS-cursor scatter to final per-node order with
// w*dinv[col] folded in.
__global__ __launch_bounds__(256) void bucket_kernel(const uint2* __restrict__ bedge,
                                                     const int* __restrict__ gbase,
                                                     int* __restrict__ rowptr,
                                                     float* __restrict__ dinv,
                                                     uint2* __restrict__ sedge,
                                                     int N, int E, int nblk, int nbuck) {
    __shared__ int lcnt[256];
    __shared__ float lw[256];
    __shared__ int lscan[256];
    __shared__ int lcur[256];
    __shared__ float ldv[256];

    const int d = blockIdx.x, t = threadIdx.x;
    const int base = gbase[d * nblk];
    const int end  = (d == nbuck - 1) ? E : gbase[(d + 1) * nblk];

    lcnt[t] = 0;
    lw[t] = 0.f;
    __syncthreads();
    for (int i = base + t; i < end; i += 256) {
        uint2 p = bedge[i];
        int c = (p.x >> 16) & 255;
        atomicAdd(&lcnt[c], 1);
        atomicAdd(&lw[c], __uint_as_float(p.y));
    }
    __syncthreads();
    int own = lcnt[t];
    lscan[t] = own;
    for (int off = 1; off < 256; off <<= 1) {
        __syncthreads();
        int v = (t >= off) ? lscan[t - off] : 0;
        __syncthreads();
        lscan[t] += v;
    }
    __syncthreads();
    int excl = lscan[t] - own;
    lcur[t] = base + excl;
    float wsum = lw[t];
    float dv = (wsum > 0.f) ? rsqrtf(wsum) : 0.f;
    ldv[t] = dv;
    int node = d * 256 + t;
    if (node < N) {
        rowptr[node] = base + excl;
        dinv[node] = dv;
    }
    if (d == nbuck - 1 && t == 0) rowptr[N] = E;
    __syncthreads();
    for (int i = base + t; i < end; i += 256) {
        uint2 p = bedge[i];
        int c = (p.x >> 16) & 255;
        int slot = atomicAdd(&lcur[c], 1);
        sedge[slot] = make_uint2(p.x & 0xFFFFu,
                                 __float_as_uint(__uint_as_float(p.y) * ldv[c]));
    }
}

// K5: finish norm: w *= dinv[row]  (dinv is 200KB, L2-resident)
__global__ void norm_kernel(uint2* __restrict__ sedge, const float* __restrict__ dinv, int E) {
    int i = blockIdx.x * blockDim.x + threadIdx.x;
    if (i < E) {
        uint2 p = sedge[i];
        p.y = __float_as_uint(__uint_as_float(p.y) * dinv[p.x]);
        sedge[i] = p;
    }
}

// all 3 weights -> transposed split planes Wt[c][k] bf16 hi/lo, one launch
__global__ void convw_kernel(const float* __restrict__ W0, const float* __restrict__ W1,
                             const float* __restrict__ W2,
                             unsigned short* __restrict__ Whi, unsigned short* __restrict__ Wlo) {
    int i = blockIdx.x * blockDim.x + threadIdx.x;  // 16384 per weight
    int which = blockIdx.y;
    const float* W = (which == 0) ? W0 : (which == 1) ? W1 : W2;
    int c = i >> 7, k = i & 127;
    float w = W[(size_t)k * FEAT + c];
    unsigned int h = bf16rtn(w);
    size_t off = (size_t)which * 16384 + (size_t)c * FEAT + k;
    Whi[off] = (unsigned short)h;
    Wlo[off] = (unsigned short)bf16rtn(w - bf16tof(h));
}

// ---------------------------------------------------------------- MFMA GEMM (R7 form)
__global__ __launch_bounds__(256) void gemm_mfma_kernel(
    const float* __restrict__ X,
    const unsigned short* __restrict__ Wthi, const unsigned short* __restrict__ Wtlo,
    unsigned int* __restrict__ hb,   // N x 64 packed bf16 out
    int N)
{
    __shared__ unsigned short xh[64 * 128];
    __shared__ unsigned short xl[64 * 128];
    __shared__ unsigned short wh[64 * 128];
    __shared__ unsigned short wl[64 * 128];

    const int tid = threadIdx.x;
    const int r0 = blockIdx.x * 64;
    const int cb = blockIdx.y;       // col half: 0 or 1

#pragma unroll
    for (int it = 0; it < 4; ++it) {
        int idx = it * 256 + tid;
        int c = idx >> 4;
        int k8 = (idx & 15) * 8;
        int sw = k8 ^ ((c & 7) << 3);
        size_t src = (size_t)(cb * 64 + c) * FEAT + k8;
        *(short8*)&wh[c * 128 + sw] = *(const short8*)(Wthi + src);
        *(short8*)&wl[c * 128 + sw] = *(const short8*)(Wtlo + src);
    }
#pragma unroll
    for (int it = 0; it < 8; ++it) {
        int idx = it * 256 + tid;
        int r = idx >> 5;
        int kc = (idx & 31) * 4;
        int gr = r0 + r;
        float4 v = make_float4(0.f, 0.f, 0.f, 0.f);
        if (gr < N) v = *(const float4*)(X + (size_t)gr * FEAT + kc);
        unsigned int h0 = bf16rtn(v.x), h1 = bf16rtn(v.y);
        unsigned int h2 = bf16rtn(v.z), h3 = bf16rtn(v.w);
        ushort4 hv = make_ushort4((unsigned short)h0, (unsigned short)h1,
                                  (unsigned short)h2, (unsigned short)h3);
        ushort4 lv = make_ushort4((unsigned short)bf16rtn(v.x - bf16tof(h0)),
                                  (unsigned short)bf16rtn(v.y - bf16tof(h1)),
                                  (unsigned short)bf16rtn(v.z - bf16tof(h2)),
                                  (unsigned short)bf16rtn(v.w - bf16tof(h3)));
        int sw = kc ^ ((r & 7) << 3);
        *(ushort4*)&xh[r * 128 + sw] = hv;
        *(ushort4*)&xl[r * 128 + sw] = lv;
    }
    __syncthreads();

    const int lane = tid & 63;
    const int wv = tid >> 6;
    const int m = lane & 15;
    const int quad = lane >> 4;
    const int arow = wv * 16 + m;

    f32x4 acc[4];
#pragma unroll
    for (int ct = 0; ct < 4; ++ct) acc[ct] = (f32x4){0.f, 0.f, 0.f, 0.f};

#pragma unroll
    for (int kt = 0; kt < 4; ++kt) {
        const int k0 = kt * 32 + quad * 8;
        const int aw = k0 ^ ((arow & 7) << 3);
        short8 ah = *(const short8*)&xh[arow * 128 + aw];
        short8 al = *(const short8*)&xl[arow * 128 + aw];
#pragma unroll
        for (int ct = 0; ct < 4; ++ct) {
            int bc = ct * 16 + m;
            int bw = k0 ^ ((bc & 7) << 3);
            short8 bh = *(const short8*)&wh[bc * 128 + bw];
            short8 bl = *(const short8*)&wl[bc * 128 + bw];
            acc[ct] = __builtin_amdgcn_mfma_f32_16x16x32_bf16(ah, bh, acc[ct], 0, 0, 0);
            acc[ct] = __builtin_amdgcn_mfma_f32_16x16x32_bf16(ah, bl, acc[ct], 0, 0, 0);
            acc[ct] = __builtin_amdgcn_mfma_f32_16x16x32_bf16(al, bh, acc[ct], 0, 0, 0);
        }
    }

    __syncthreads();
    unsigned short* cl = xh;
#pragma unroll
    for (int ct = 0; ct < 4; ++ct)
#pragma unroll
        for (int reg = 0; reg < 4; ++reg) {
            int rrow = wv * 16 + quad * 4 + reg;
            cl[rrow * 72 + ct * 16 + m] = (unsigned short)bf16rtn(acc[ct][reg]);
        }
    __syncthreads();
#pragma unroll
    for (int it = 0; it < 2; ++it) {
        int idx = it * 256 + tid;
        int r = idx >> 3;
        int c4 = (idx & 7) * 4;
        int gr = r0 + r;
        if (gr < N) {
            uint4 pv = *(const uint4*)&cl[r * 72 + c4 * 2];
            *(uint4*)(hb + (size_t)gr * 64 + cb * 32 + c4) = pv;
        }
    }
}

// ---------------------------------------------------------------- CSR aggregation v4 (R7 form)
template <int RELU>
__global__ __launch_bounds__(256) void agg_kernel(
    const int* __restrict__ rowptr, const uint2* __restrict__ sedge,
    const unsigned int* __restrict__ hb, const float* __restrict__ bias,
    float* __restrict__ outX, int N)
{
    const int node = blockIdx.x * 4 + (threadIdx.x >> 6);
    if (node >= N) return;
    const int lane = threadIdx.x & 63;
    const int s = rowptr[node];
    const int e = rowptr[node + 1];

    float2 bv = *(const float2*)(bias + lane * 2);
    float a0 = bv.x, a1 = bv.y;

    int i = s;
    const int nfull = (e - s) >> 3;
    if (nfull > 0) {
        uint2 c0 = sedge[i], c1 = sedge[i + 1], c2 = sedge[i + 2], c3 = sedge[i + 3];
        uint2 c4 = sedge[i + 4], c5 = sedge[i + 5], c6 = sedge[i + 6], c7 = sedge[i + 7];
        for (int g = 0; g < nfull; ++g) {
            unsigned v0 = hb[(size_t)c0.x * 64 + lane];
            unsigned v1 = hb[(size_t)c1.x * 64 + lane];
            unsigned v2 = hb[(size_t)c2.x * 64 + lane];
            unsigned v3 = hb[(size_t)c3.x * 64 + lane];
            unsigned v4 = hb[(size_t)c4.x * 64 + lane];
            unsigned v5 = hb[(size_t)c5.x * 64 + lane];
            unsigned v6 = hb[(size_t)c6.x * 64 + lane];
            unsigned v7 = hb[(size_t)c7.x * 64 + lane];
            float w0 = __uint_as_float(c0.y), w1 = __uint_as_float(c1.y);
            float w2 = __uint_as_float(c2.y), w3 = __uint_as_float(c3.y);
            float w4 = __uint_as_float(c4.y), w5 = __uint_as_float(c5.y);
            float w6 = __uint_as_float(c6.y), w7 = __uint_as_float(c7.y);
            int ni = i + 8;
            if (g + 1 < nfull) {   // prefetch next metadata (wave-uniform branch)
                c0 = sedge[ni];     c1 = sedge[ni + 1];
                c2 = sedge[ni + 2]; c3 = sedge[ni + 3];
                c4 = sedge[ni + 4]; c5 = sedge[ni + 5];
                c6 = sedge[ni + 6]; c7 = sedge[ni + 7];
            }
            a0 = fmaf(w0, bf16lo(v0), a0);  a1 = fmaf(w0, bf16hi(v0), a1);
            a0 = fmaf(w1, bf16lo(v1), a0);  a1 = fmaf(w1, bf16hi(v1), a1);
            a0 = fmaf(w2, bf16lo(v2), a0);  a1 = fmaf(w2, bf16hi(v2), a1);
            a0 = fmaf(w3, bf16lo(v3), a0);  a1 = fmaf(w3, bf16hi(v3), a1);
            a0 = fmaf(w4, bf16lo(v4), a0);  a1 = fmaf(w4, bf16hi(v4), a1);
            a0 = fmaf(w5, bf16lo(v5), a0);  a1 = fmaf(w5, bf16hi(v5), a1);
            a0 = fmaf(w6, bf16lo(v6), a0);  a1 = fmaf(w6, bf16hi(v6), a1);
            a0 = fmaf(w7, bf16lo(v7), a0);  a1 = fmaf(w7, bf16hi(v7), a1);
            i = ni;
        }
    }
    for (; i < e; ++i) {
        uint2 p = sedge[i];
        unsigned v = hb[(size_t)p.x * 64 + lane];
        float w = __uint_as_float(p.y);
        a0 = fmaf(w, bf16lo(v), a0);
        a1 = fmaf(w, bf16hi(v), a1);
    }

    if (RELU) { a0 = fmaxf(a0, 0.f); a1 = fmaxf(a1, 0.f); }
    *(float2*)(outX + (size_t)node * FEAT + lane * 2) = make_float2(a0, a1);
}

// ---------------------------------------------------------------- readout v2 (R8 form — verified good)
// grid (G, 8): 8 chunks per graph, 4-deep ILP, one atomicAdd per thread.
__global__ __launch_bounds__(128) void readout_kernel(const float* __restrict__ h,
                                                      const int* __restrict__ batch,
                                                      float* __restrict__ ro, int N) {
    const int g = blockIdx.x;
    const int chunk = blockIdx.y;
    const int j = threadIdx.x;
    int lo = 0, hi = N;
    while (lo < hi) { int mid = (lo + hi) >> 1; if (batch[mid] < g) lo = mid + 1; else hi = mid; }
    int lo2 = lo, hi2 = N;
    while (lo2 < hi2) { int mid = (lo2 + hi2) >> 1; if (batch[mid] < g + 1) lo2 = mid + 1; else hi2 = mid; }
    const int len = lo2 - lo;
    const int per = (len + 7) >> 3;
    const int cs = lo + chunk * per;
    const int ce = min(lo2, cs + per);

    float s0 = 0.f, s1 = 0.f, s2 = 0.f, s3 = 0.f;
    int n = cs;
    for (; n + 4 <= ce; n += 4) {
        s0 += h[(size_t)n * FEAT + j];
        s1 += h[(size_t)(n + 1) * FEAT + j];
        s2 += h[(size_t)(n + 2) * FEAT + j];
        s3 += h[(size_t)(n + 3) * FEAT + j];
    }
    for (; n < ce; ++n) s0 += h[(size_t)n * FEAT + j];
    float acc = (s0 + s1) + (s2 + s3);
    if (cs < ce) atomicAdd(&ro[(size_t)g * FEAT + j], acc);
}

// ---------------------------------------------------------------- launch
static inline size_t align256(size_t x) { return (x + 255) & ~(size_t)255; }

extern "C" void kernel_launch(void* const* d_in, const int* in_sizes, int n_in,
                              void* d_out, int out_size, void* d_ws, size_t ws_size,
                              hipStream_t stream) {
    const float* gx    = (const float*)d_in[0];
    const int*   ei    = (const int*)d_in[1];
    const int*   batch = (const int*)d_in[2];
    const float* ew    = (const float*)d_in[3];
    const float* W1 = (const float*)d_in[4];
    const float* b1 = (const float*)d_in[5];
    const float* W2 = (const float*)d_in[6];
    const float* b2 = (const float*)d_in[7];
    const float* W3 = (const float*)d_in[8];
    const float* b3 = (const float*)d_in[9];

    const int N = in_sizes[0] / FEAT;            // 50000
    const int E = in_sizes[3];                   // 800000
    const int G = (out_size - N * FEAT) / FEAT;  // 256

    const int* row = ei;
    const int* col = ei + E;

    const int nbuck = (N + 255) >> 8;            // 196
    const int nblk  = (E + 4095) >> 12;          // 196
    const int M     = nbuck * nblk;              // 38416

    // ---- workspace layout
    char* ws = (char*)d_ws;
    int*   rowptr = (int*)ws;         ws += align256((size_t)(N + 1) * 4);
    float* dinv   = (float*)ws;       ws += align256((size_t)N * 4);
    int*   ghist  = (int*)ws;         ws += align256((size_t)M * 4);
    int*   gbase  = (int*)ws;         ws += align256((size_t)(M + 1) * 4);
    int*   bsum   = (int*)ws;         ws += align256(256 * 4);
    uint2* bedge  = (uint2*)ws;       ws += align256((size_t)E * 8);
    uint2* sedge  = (uint2*)ws;       ws += align256((size_t)E * 8);
    unsigned int* hb = (unsigned int*)ws;  ws += align256((size_t)N * 64 * 4);
    float* bufX   = (float*)ws;       ws += align256((size_t)N * FEAT * 4);
    unsigned short* Wh = (unsigned short*)ws; ws += align256((size_t)3 * 16384 * 2);
    unsigned short* Wl = (unsigned short*)ws; ws += align256((size_t)3 * 16384 * 2);

    float* h_out = (float*)d_out;
    float* ro    = h_out + (size_t)N * FEAT;

    // ---- bucket-sorted CSR build (no global atomics)
    hist_kernel<<<nblk, 256, 0, stream>>>(col, ghist, E, nblk, nbuck);
    const int snb = (M + 255) / 256;
    scan_block_kernel<<<snb, 256, 0, stream>>>(ghist, gbase, bsum, M);
    scan_bsum_kernel<<<1, 256, 0, stream>>>(bsum, snb);
    scan_add_kernel<<<snb + 1, 256, 0, stream>>>(gbase, bsum, M, E);
    scatter1_kernel<<<nblk, 256, 0, stream>>>(row, col, ew, gbase, bedge, E, nblk, nbuck);
    bucket_kernel<<<nbuck, 256, 0, stream>>>(bedge, gbase, rowptr, dinv, sedge, N, E, nblk, nbuck);
    norm_kernel<<<(E + 255) / 256, 256, 0, stream>>>(sedge, dinv, E);

    // ---- weight conversion (one launch, 3 weights)
    convw_kernel<<<dim3(64, 3), 256, 0, stream>>>(W1, W2, W3, Wh, Wl);

    dim3 ggrid((N + 63) / 64, 2);
    const int ablocks = (N + 3) / 4;

    // ---- layer 1 (GEMM reads gx fp32 directly)
    gemm_mfma_kernel<<<ggrid, 256, 0, stream>>>(gx, Wh, Wl, hb, N);
    agg_kernel<1><<<ablocks, 256, 0, stream>>>(rowptr, sedge, hb, b1, bufX, N);
    // ---- layer 2
    gemm_mfma_kernel<<<ggrid, 256, 0, stream>>>(bufX, Wh + 16384, Wl + 16384, hb, N);
    agg_kernel<1><<<ablocks, 256, 0, stream>>>(rowptr, sedge, hb, b2, bufX, N);
    // ---- layer 3
    gemm_mfma_kernel<<<ggrid, 256, 0, stream>>>(bufX, Wh + 32768, Wl + 32768, hb, N);
    agg_kernel<0><<<ablocks, 256, 0, stream>>>(rowptr, sedge, hb, b3, h_out, N);
    // ---- readout: parallel chunked segment-sum (sorted batch)
    zero_kernel<<<(G * FEAT + 255) / 256, 256, 0, stream>>>(ro, G * FEAT);
    readout_kernel<<<dim3(G, 8), 128, 0, stream>>>(h_out, batch, ro, N);
}

// Round 10
// 311.399 us; speedup vs baseline: 1.5002x; 1.0655x over previous
//
#include <hip/hip_runtime.h>

#define FEAT 128

typedef __attribute__((ext_vector_type(8))) short short8;   // 8 bf16 = 4 VGPRs
typedef __attribute__((ext_vector_type(4))) float f32x4;

__device__ __forceinline__ unsigned int bf16rtn(float f) {
    unsigned int u = __float_as_uint(f);
    return (u + 0x7fffu + ((u >> 16) & 1u)) >> 16;   // round-to-nearest-even
}
__device__ __forceinline__ float bf16tof(unsigned int h) { return __uint_as_float(h << 16); }
__device__ __forceinline__ float bf16lo(unsigned int v) { return __uint_as_float(v << 16); }
__device__ __forceinline__ float bf16hi(unsigned int v) { return __uint_as_float(v & 0xffff0000u); }

// ---------------------------------------------------------------- utilities
__global__ void zero_kernel(float* __restrict__ p, int n) {
    int i = blockIdx.x * blockDim.x + threadIdx.x;
    if (i < n) p[i] = 0.0f;
}

// ---------------------------------------------------------------- bucket sort (no global atomics)
// K1: per-block LDS histogram over col>>8 (nbuck buckets), 4096 edges/block.
__global__ __launch_bounds__(256) void hist_kernel(const int* __restrict__ col,
                                                   int* __restrict__ ghist,
                                                   int E, int nblk, int nbuck) {
    __shared__ int h[256];
    const int t = threadIdx.x, b = blockIdx.x;
    h[t] = 0;
    __syncthreads();
    const int base = b * 4096;
#pragma unroll
    for (int i = 0; i < 16; ++i) {
        int e = base + i * 256 + t;
        if (e < E) atomicAdd(&h[col[e] >> 8], 1);
    }
    __syncthreads();
    if (t < nbuck) ghist[t * nblk + b] = h[t];   // digit-major for the scan
}

// ---------------------------------------------------------------- scan (exclusive, 2 kernels; block
// offsets folded into consumers)
__global__ __launch_bounds__(256) void scan_block_kernel(const int* __restrict__ cnt,
                                                         int* __restrict__ out,
                                                         int* __restrict__ bsum, int M) {
    __shared__ int s[256];
    int t = threadIdx.x;
    int i = blockIdx.x * 256 + t;
    int own = (i < M) ? cnt[i] : 0;
    s[t] = own;
    for (int off = 1; off < 256; off <<= 1) {
        __syncthreads();
        int v = (t >= off) ? s[t - off] : 0;
        __syncthreads();
        s[t] += v;
    }
    __syncthreads();
    if (i < M) out[i] = s[t] - own;
    if (t == 255) bsum[blockIdx.x] = s[255];
}

__global__ __launch_bounds__(256) void scan_bsum_kernel(int* __restrict__ bsum, int nb) {
    __shared__ int s[256];
    int t = threadIdx.x;
    int own = (t < nb) ? bsum[t] : 0;
    s[t] = own;
    for (int off = 1; off < 256; off <<= 1) {
        __syncthreads();
        int v = (t >= off) ? s[t - off] : 0;
        __syncthreads();
        s[t] += v;
    }
    __syncthreads();
    if (t < nb) bsum[t] = s[t] - own;
}

// K3: scatter into bucket-grouped order. LDS cursors seeded from scanned hist
// (+ folded block offset). payload: x = (col<<16) | row, y = ew bits.
__global__ __launch_bounds__(256) void scatter1_kernel(const int* __restrict__ row,
                                                       const int* __restrict__ col,
                                                       const float* __restrict__ ew,
                                                       const int* __restrict__ gsc,
                                                       const int* __restrict__ bsum,
                                                       uint2* __restrict__ bedge,
                                                       int E, int nblk, int nbuck) {
    __shared__ int cur[256];
    const int t = threadIdx.x, b = blockIdx.x;
    if (t < nbuck) {
        int idx = t * nblk + b;
        cur[t] = gsc[idx] + bsum[idx >> 8];
    }
    __syncthreads();
    const int base = b * 4096;
#pragma unroll
    for (int i = 0; i < 16; ++i) {
        int e = base + i * 256 + t;
        if (e < E) {
            int c = col[e];
            int slot = atomicAdd(&cur[c >> 8], 1);
            bedge[slot] = make_uint2(((unsigned)c << 16) | (unsigned)row[e],
                                     __float_as_uint(ew[e]));
        }
    }
}

// K4: one block per bucket (256 nodes). LDS count + weighted-degree sum per
// node -> rowptr + dinv; then LDS-cursor scatter to final per-node order with
// w*dinv[col] folded in.
__global__ __launch_bounds__(256) void bucket_kernel(const uint2* __restrict__ bedge,
                                                     const int* __restrict__ gsc,
                                                     const int* __restrict__ bsum,
                                                     int* __restrict__ rowptr,
                                                     float* __restrict__ dinv,
                                                     uint2* __restrict__ sedge,
                                                     int N, int E, int nblk, int nbuck) {
    __shared__ int lcnt[256];
    __shared__ float lw[256];
    __shared__ int lscan[256];
    __shared__ int lcur[256];
    __shared__ float ldv[256];

    const int d = blockIdx.x, t = threadIdx.x;
    const int i0 = d * nblk;
    const int base = gsc[i0] + bsum[i0 >> 8];
    int end;
    if (d == nbuck - 1) end = E;
    else {
        const int i1 = (d + 1) * nblk;
        end = gsc[i1] + bsum[i1 >> 8];
    }

    lcnt[t] = 0;
    lw[t] = 0.f;
    __syncthreads();
    for (int i = base + t; i < end; i += 256) {
        uint2 p = bedge[i];
        int c = (p.x >> 16) & 255;
        atomicAdd(&lcnt[c], 1);
        atomicAdd(&lw[c], __uint_as_float(p.y));
    }
    __syncthreads();
    int own = lcnt[t];
    lscan[t] = own;
    for (int off = 1; off < 256; off <<= 1) {
        __syncthreads();
        int v = (t >= off) ? lscan[t - off] : 0;
        __syncthreads();
        lscan[t] += v;
    }
    __syncthreads();
    int excl = lscan[t] - own;
    lcur[t] = base + excl;
    float wsum = lw[t];
    float dv = (wsum > 0.f) ? rsqrtf(wsum) : 0.f;
    ldv[t] = dv;
    int node = d * 256 + t;
    if (node < N) {
        rowptr[node] = base + excl;
        dinv[node] = dv;
    }
    if (d == nbuck - 1 && t == 0) rowptr[N] = E;
    __syncthreads();
    for (int i = base + t; i < end; i += 256) {
        uint2 p = bedge[i];
        int c = (p.x >> 16) & 255;
        int slot = atomicAdd(&lcur[c], 1);
        sedge[slot] = make_uint2(p.x & 0xFFFFu,
                                 __float_as_uint(__uint_as_float(p.y) * ldv[c]));
    }
}

// K5: finish norm: w *= dinv[row]  (dinv is 200KB, L2-resident)
__global__ void norm_kernel(uint2* __restrict__ sedge, const float* __restrict__ dinv, int E) {
    int i = blockIdx.x * blockDim.x + threadIdx.x;
    if (i < E) {
        uint2 p = sedge[i];
        p.y = __float_as_uint(__uint_as_float(p.y) * dinv[p.x]);
        sedge[i] = p;
    }
}

// all 3 weights -> transposed split planes Wt[c][k] bf16 hi/lo, one launch
__global__ void convw_kernel(const float* __restrict__ W0, const float* __restrict__ W1,
                             const float* __restrict__ W2,
                             unsigned short* __restrict__ Whi, unsigned short* __restrict__ Wlo) {
    int i = blockIdx.x * blockDim.x + threadIdx.x;  // 16384 per weight
    int which = blockIdx.y;
    const float* W = (which == 0) ? W0 : (which == 1) ? W1 : W2;
    int c = i >> 7, k = i & 127;
    float w = W[(size_t)k * FEAT + c];
    unsigned int h = bf16rtn(w);
    size_t off = (size_t)which * 16384 + (size_t)c * FEAT + k;
    Whi[off] = (unsigned short)h;
    Wlo[off] = (unsigned short)bf16rtn(w - bf16tof(h));
}

// ---------------------------------------------------------------- MFMA GEMM (R7 form)
__global__ __launch_bounds__(256) void gemm_mfma_kernel(
    const float* __restrict__ X,
    const unsigned short* __restrict__ Wthi, const unsigned short* __restrict__ Wtlo,
    unsigned int* __restrict__ hb,   // N x 64 packed bf16 out
    int N)
{
    __shared__ unsigned short xh[64 * 128];
    __shared__ unsigned short xl[64 * 128];
    __shared__ unsigned short wh[64 * 128];
    __shared__ unsigned short wl[64 * 128];

    const int tid = threadIdx.x;
    const int r0 = blockIdx.x * 64;
    const int cb = blockIdx.y;       // col half: 0 or 1

#pragma unroll
    for (int it = 0; it < 4; ++it) {
        int idx = it * 256 + tid;
        int c = idx >> 4;
        int k8 = (idx & 15) * 8;
        int sw = k8 ^ ((c & 7) << 3);
        size_t src = (size_t)(cb * 64 + c) * FEAT + k8;
        *(short8*)&wh[c * 128 + sw] = *(const short8*)(Wthi + src);
        *(short8*)&wl[c * 128 + sw] = *(const short8*)(Wtlo + src);
    }
#pragma unroll
    for (int it = 0; it < 8; ++it) {
        int idx = it * 256 + tid;
        int r = idx >> 5;
        int kc = (idx & 31) * 4;
        int gr = r0 + r;
        float4 v = make_float4(0.f, 0.f, 0.f, 0.f);
        if (gr < N) v = *(const float4*)(X + (size_t)gr * FEAT + kc);
        unsigned int h0 = bf16rtn(v.x), h1 = bf16rtn(v.y);
        unsigned int h2 = bf16rtn(v.z), h3 = bf16rtn(v.w);
        ushort4 hv = make_ushort4((unsigned short)h0, (unsigned short)h1,
                                  (unsigned short)h2, (unsigned short)h3);
        ushort4 lv = make_ushort4((unsigned short)bf16rtn(v.x - bf16tof(h0)),
                                  (unsigned short)bf16rtn(v.y - bf16tof(h1)),
                                  (unsigned short)bf16rtn(v.z - bf16tof(h2)),
                                  (unsigned short)bf16rtn(v.w - bf16tof(h3)));
        int sw = kc ^ ((r & 7) << 3);
        *(ushort4*)&xh[r * 128 + sw] = hv;
        *(ushort4*)&xl[r * 128 + sw] = lv;
    }
    __syncthreads();

    const int lane = tid & 63;
    const int wv = tid >> 6;
    const int m = lane & 15;
    const int quad = lane >> 4;
    const int arow = wv * 16 + m;

    f32x4 acc[4];
#pragma unroll
    for (int ct = 0; ct < 4; ++ct) acc[ct] = (f32x4){0.f, 0.f, 0.f, 0.f};

#pragma unroll
    for (int kt = 0; kt < 4; ++kt) {
        const int k0 = kt * 32 + quad * 8;
        const int aw = k0 ^ ((arow & 7) << 3);
        short8 ah = *(const short8*)&xh[arow * 128 + aw];
        short8 al = *(const short8*)&xl[arow * 128 + aw];
#pragma unroll
        for (int ct = 0; ct < 4; ++ct) {
            int bc = ct * 16 + m;
            int bw = k0 ^ ((bc & 7) << 3);
            short8 bh = *(const short8*)&wh[bc * 128 + bw];
            short8 bl = *(const short8*)&wl[bc * 128 + bw];
            acc[ct] = __builtin_amdgcn_mfma_f32_16x16x32_bf16(ah, bh, acc[ct], 0, 0, 0);
            acc[ct] = __builtin_amdgcn_mfma_f32_16x16x32_bf16(ah, bl, acc[ct], 0, 0, 0);
            acc[ct] = __builtin_amdgcn_mfma_f32_16x16x32_bf16(al, bh, acc[ct], 0, 0, 0);
        }
    }

    __syncthreads();
    unsigned short* cl = xh;
#pragma unroll
    for (int ct = 0; ct < 4; ++ct)
#pragma unroll
        for (int reg = 0; reg < 4; ++reg) {
            int rrow = wv * 16 + quad * 4 + reg;
            cl[rrow * 72 + ct * 16 + m] = (unsigned short)bf16rtn(acc[ct][reg]);
        }
    __syncthreads();
#pragma unroll
    for (int it = 0; it < 2; ++it) {
        int idx = it * 256 + tid;
        int r = idx >> 3;
        int c4 = (idx & 7) * 4;
        int gr = r0 + r;
        if (gr < N) {
            uint4 pv = *(const uint4*)&cl[r * 72 + c4 * 2];
            *(uint4*)(hb + (size_t)gr * 64 + cb * 32 + c4) = pv;
        }
    }
}

// ---------------------------------------------------------------- CSR aggregation v6
// One wave per node (4/block). lane = 32*h + j: parity h handles even/odd
// edges, lane loads uint2 (features 4j..4j+3) -> ONE gather instruction
// serves 2 edges (512B). 16-edge groups: 8 gathers in flight. Metadata loads
// are half-wave-uniform adjacent pairs (no shfl). Tail = guarded last group
// (row=0, w=0 fallback) so all 8 loads always issue. Cross-parity shfl_xor
// reduce; lanes 0-31 add bias (+relu), store float4.
template <int RELU>
__global__ __launch_bounds__(256) void agg_kernel(
    const int* __restrict__ rowptr, const uint2* __restrict__ sedge,
    const uint2* __restrict__ hb2,   // N x 32 uint2 rows (256B packed bf16)
    const float* __restrict__ bias,
    float* __restrict__ outX, int N)
{
    const int node = blockIdx.x * 4 + (threadIdx.x >> 6);
    if (node >= N) return;
    const int lane = threadIdx.x & 63;
    const int h = lane >> 5;
    const int j = lane & 31;
    const int s = rowptr[node];
    const int e = rowptr[node + 1];

    float a0 = 0.f, a1 = 0.f, a2 = 0.f, a3 = 0.f;

    for (int gb = s; gb < e; gb += 16) {
        uint2 m0, m1, m2, m3, m4, m5, m6, m7;
        if (gb + 16 <= e) {
            m0 = sedge[gb + 0 + h];  m1 = sedge[gb + 2 + h];
            m2 = sedge[gb + 4 + h];  m3 = sedge[gb + 6 + h];
            m4 = sedge[gb + 8 + h];  m5 = sedge[gb + 10 + h];
            m6 = sedge[gb + 12 + h]; m7 = sedge[gb + 14 + h];
        } else {
            const uint2 z = make_uint2(0u, 0u);
            int i0 = gb + 0 + h, i1 = gb + 2 + h, i2 = gb + 4 + h, i3 = gb + 6 + h;
            int i4 = gb + 8 + h, i5 = gb + 10 + h, i6 = gb + 12 + h, i7 = gb + 14 + h;
            m0 = (i0 < e) ? sedge[i0] : z;  m1 = (i1 < e) ? sedge[i1] : z;
            m2 = (i2 < e) ? sedge[i2] : z;  m3 = (i3 < e) ? sedge[i3] : z;
            m4 = (i4 < e) ? sedge[i4] : z;  m5 = (i5 < e) ? sedge[i5] : z;
            m6 = (i6 < e) ? sedge[i6] : z;  m7 = (i7 < e) ? sedge[i7] : z;
        }
        uint2 v0 = hb2[(size_t)m0.x * 32 + j];
        uint2 v1 = hb2[(size_t)m1.x * 32 + j];
        uint2 v2 = hb2[(size_t)m2.x * 32 + j];
        uint2 v3 = hb2[(size_t)m3.x * 32 + j];
        uint2 v4 = hb2[(size_t)m4.x * 32 + j];
        uint2 v5 = hb2[(size_t)m5.x * 32 + j];
        uint2 v6 = hb2[(size_t)m6.x * 32 + j];
        uint2 v7 = hb2[(size_t)m7.x * 32 + j];
        float w0 = __uint_as_float(m0.y), w1 = __uint_as_float(m1.y);
        float w2 = __uint_as_float(m2.y), w3 = __uint_as_float(m3.y);
        float w4 = __uint_as_float(m4.y), w5 = __uint_as_float(m5.y);
        float w6 = __uint_as_float(m6.y), w7 = __uint_as_float(m7.y);
        a0 = fmaf(w0, bf16lo(v0.x), a0); a1 = fmaf(w0, bf16hi(v0.x), a1);
        a2 = fmaf(w0, bf16lo(v0.y), a2); a3 = fmaf(w0, bf16hi(v0.y), a3);
        a0 = fmaf(w1, bf16lo(v1.x), a0); a1 = fmaf(w1, bf16hi(v1.x), a1);
        a2 = fmaf(w1, bf16lo(v1.y), a2); a3 = fmaf(w1, bf16hi(v1.y), a3);
        a0 = fmaf(w2, bf16lo(v2.x), a0); a1 = fmaf(w2, bf16hi(v2.x), a1);
        a2 = fmaf(w2, bf16lo(v2.y), a2); a3 = fmaf(w2, bf16hi(v2.y), a3);
        a0 = fmaf(w3, bf16lo(v3.x), a0); a1 = fmaf(w3, bf16hi(v3.x), a1);
        a2 = fmaf(w3, bf16lo(v3.y), a2); a3 = fmaf(w3, bf16hi(v3.y), a3);
        a0 = fmaf(w4, bf16lo(v4.x), a0); a1 = fmaf(w4, bf16hi(v4.x), a1);
        a2 = fmaf(w4, bf16lo(v4.y), a2); a3 = fmaf(w4, bf16hi(v4.y), a3);
        a0 = fmaf(w5, bf16lo(v5.x), a0); a1 = fmaf(w5, bf16hi(v5.x), a1);
        a2 = fmaf(w5, bf16lo(v5.y), a2); a3 = fmaf(w5, bf16hi(v5.y), a3);
        a0 = fmaf(w6, bf16lo(v6.x), a0); a1 = fmaf(w6, bf16hi(v6.x), a1);
        a2 = fmaf(w6, bf16lo(v6.y), a2); a3 = fmaf(w6, bf16hi(v6.y), a3);
        a0 = fmaf(w7, bf16lo(v7.x), a0); a1 = fmaf(w7, bf16hi(v7.x), a1);
        a2 = fmaf(w7, bf16lo(v7.y), a2); a3 = fmaf(w7, bf16hi(v7.y), a3);
    }

    // combine even/odd-edge partials (feature slots identical across parity)
    a0 += __shfl_xor(a0, 32);
    a1 += __shfl_xor(a1, 32);
    a2 += __shfl_xor(a2, 32);
    a3 += __shfl_xor(a3, 32);

    if (h == 0) {
        float4 bv = ((const float4*)bias)[j];
        a0 += bv.x; a1 += bv.y; a2 += bv.z; a3 += bv.w;
        if (RELU) {
            a0 = fmaxf(a0, 0.f); a1 = fmaxf(a1, 0.f);
            a2 = fmaxf(a2, 0.f); a3 = fmaxf(a3, 0.f);
        }
        *(float4*)(outX + (size_t)node * FEAT + j * 4) = make_float4(a0, a1, a2, a3);
    }
}

// ---------------------------------------------------------------- readout v2 (R8 form — verified good)
__global__ __launch_bounds__(128) void readout_kernel(const float* __restrict__ h,
                                                      const int* __restrict__ batch,
                                                      float* __restrict__ ro, int N) {
    const int g = blockIdx.x;
    const int chunk = blockIdx.y;
    const int j = threadIdx.x;
    int lo = 0, hi = N;
    while (lo < hi) { int mid = (lo + hi) >> 1; if (batch[mid] < g) lo = mid + 1; else hi = mid; }
    int lo2 = lo, hi2 = N;
    while (lo2 < hi2) { int mid = (lo2 + hi2) >> 1; if (batch[mid] < g + 1) lo2 = mid + 1; else hi2 = mid; }
    const int len = lo2 - lo;
    const int per = (len + 7) >> 3;
    const int cs = lo + chunk * per;
    const int ce = min(lo2, cs + per);

    float s0 = 0.f, s1 = 0.f, s2 = 0.f, s3 = 0.f;
    int n = cs;
    for (; n + 4 <= ce; n += 4) {
        s0 += h[(size_t)n * FEAT + j];
        s1 += h[(size_t)(n + 1) * FEAT + j];
        s2 += h[(size_t)(n + 2) * FEAT + j];
        s3 += h[(size_t)(n + 3) * FEAT + j];
    }
    for (; n < ce; ++n) s0 += h[(size_t)n * FEAT + j];
    float acc = (s0 + s1) + (s2 + s3);
    if (cs < ce) atomicAdd(&ro[(size_t)g * FEAT + j], acc);
}

// ---------------------------------------------------------------- launch
static inline size_t align256(size_t x) { return (x + 255) & ~(size_t)255; }

extern "C" void kernel_launch(void* const* d_in, const int* in_sizes, int n_in,
                              void* d_out, int out_size, void* d_ws, size_t ws_size,
                              hipStream_t stream) {
    const float* gx    = (const float*)d_in[0];
    const int*   ei    = (const int*)d_in[1];
    const int*   batch = (const int*)d_in[2];
    const float* ew    = (const float*)d_in[3];
    const float* W1 = (const float*)d_in[4];
    const float* b1 = (const float*)d_in[5];
    const float* W2 = (const float*)d_in[6];
    const float* b2 = (const float*)d_in[7];
    const float* W3 = (const float*)d_in[8];
    const float* b3 = (const float*)d_in[9];

    const int N = in_sizes[0] / FEAT;            // 50000
    const int E = in_sizes[3];                   // 800000
    const int G = (out_size - N * FEAT) / FEAT;  // 256

    const int* row = ei;
    const int* col = ei + E;

    const int nbuck = (N + 255) >> 8;            // 196
    const int nblk  = (E + 4095) >> 12;          // 196
    const int M     = nbuck * nblk;              // 38416

    // ---- workspace layout
    char* ws = (char*)d_ws;
    int*   rowptr = (int*)ws;         ws += align256((size_t)(N + 1) * 4);
    float* dinv   = (float*)ws;       ws += align256((size_t)N * 4);
    int*   ghist  = (int*)ws;         ws += align256((size_t)M * 4);
    int*   gsc    = (int*)ws;         ws += align256((size_t)M * 4);
    int*   bsum   = (int*)ws;         ws += align256(256 * 4);
    uint2* bedge  = (uint2*)ws;       ws += align256((size_t)E * 8);
    uint2* sedge  = (uint2*)ws;       ws += align256((size_t)E * 8);
    unsigned int* hb = (unsigned int*)ws;  ws += align256((size_t)N * 64 * 4);
    float* bufX   = (float*)ws;       ws += align256((size_t)N * FEAT * 4);
    unsigned short* Wh = (unsigned short*)ws; ws += align256((size_t)3 * 16384 * 2);
    unsigned short* Wl = (unsigned short*)ws; ws += align256((size_t)3 * 16384 * 2);

    float* h_out = (float*)d_out;
    float* ro    = h_out + (size_t)N * FEAT;

    // ---- bucket-sorted CSR build (no global atomics)
    hist_kernel<<<nblk, 256, 0, stream>>>(col, ghist, E, nblk, nbuck);
    const int snb = (M + 255) / 256;
    scan_block_kernel<<<snb, 256, 0, stream>>>(ghist, gsc, bsum, M);
    scan_bsum_kernel<<<1, 256, 0, stream>>>(bsum, snb);
    scatter1_kernel<<<nblk, 256, 0, stream>>>(row, col, ew, gsc, bsum, bedge, E, nblk, nbuck);
    bucket_kernel<<<nbuck, 256, 0, stream>>>(bedge, gsc, bsum, rowptr, dinv, sedge, N, E, nblk, nbuck);
    norm_kernel<<<(E + 255) / 256, 256, 0, stream>>>(sedge, dinv, E);

    // ---- weight conversion (one launch, 3 weights)
    convw_kernel<<<dim3(64, 3), 256, 0, stream>>>(W1, W2, W3, Wh, Wl);

    dim3 ggrid((N + 63) / 64, 2);
    const int ablocks = (N + 3) / 4;
    const uint2* hb2 = (const uint2*)hb;

    // ---- layer 1 (GEMM reads gx fp32 directly)
    gemm_mfma_kernel<<<ggrid, 256, 0, stream>>>(gx, Wh, Wl, hb, N);
    agg_kernel<1><<<ablocks, 256, 0, stream>>>(rowptr, sedge, hb2, b1, bufX, N);
    // ---- layer 2
    gemm_mfma_kernel<<<ggrid, 256, 0, stream>>>(bufX, Wh + 16384, Wl + 16384, hb, N);
    agg_kernel<1><<<ablocks, 256, 0, stream>>>(rowptr, sedge, hb2, b2, bufX, N);
    // ---- layer 3
    gemm_mfma_kernel<<<ggrid, 256, 0, stream>>>(bufX, Wh + 32768, Wl + 32768, hb, N);
    agg_kernel<0><<<ablocks, 256, 0, stream>>>(rowptr, sedge, hb2, b3, h_out, N);
    // ---- readout: parallel chunked segment-sum (sorted batch)
    zero_kernel<<<(G * FEAT + 255) / 256, 256, 0, stream>>>(ro, G * FEAT);
    readout_kernel<<<dim3(G, 8), 128, 0, stream>>>(h_out, batch, ro, N);
}